// Round 4
// baseline (5258.034 us; speedup 1.0000x reference)
//
#include <hip/hip_runtime.h>
#include <hip/hip_fp16.h>

#define HID 128
#define LSEQ 4096
#define BATCH 64
#define EPS 1e-5f

__device__ inline unsigned short f2h(float f) {
    _Float16 h = (_Float16)f;
    return __builtin_bit_cast(unsigned short, h);
}
__device__ inline float h2f(unsigned short u) {
    return (float)__builtin_bit_cast(_Float16, u);
}

// ---------------- projection: out[b][l] = proj(tokens[b][ flip ? L-1-l : l ]) ---------
__global__ void proj_kernel(const float* __restrict__ tokens, const float* __restrict__ Wp,
                            const float* __restrict__ bp, unsigned short* __restrict__ out,
                            int flip) {
    long id = (long)blockIdx.x * 256 + threadIdx.x;    // B*L*128
    int c = (int)(id & 127);
    long row = id >> 7;
    int l = (int)(row & (LSEQ - 1));
    long b = row >> 12;
    int ls = flip ? (LSEQ - 1 - l) : l;
    const float* t = tokens + (b * LSEQ + ls) * 8;
    float acc = bp[c];
#pragma unroll
    for (int j = 0; j < 8; j++) acc += t[j] * Wp[j * 128 + c];
    out[id] = f2h(acc);
}

// ------- literal fused layer, fp32 vector ALU, weights straight from d_in -------------
// 256 threads, 32 tokens/block. thread: n = tid&127 (feature), tg = tid>>7; owns
// tokens m = 2j+tg, j in [0,16).
__global__ void layer_simple(const unsigned short* __restrict__ hin,
                             unsigned short* __restrict__ hout,
                             const float* __restrict__ W1,   // [384][128] this layer
                             const float* __restrict__ W2,   // [128][128] this layer
                             const float* __restrict__ b1, const float* __restrict__ b2,
                             const float* __restrict__ gamma, const float* __restrict__ beta) {
    __shared__ float s_h[34 * 128];   // rows l0-1 .. l0+32 (circular), fp32
    __shared__ float s_u[32 * 128];   // u after relu, then reused for x
    __shared__ float s_mu[32], s_rs[32];

    const int tid = threadIdx.x;
    const int n = tid & 127;
    const int tg = tid >> 7;

    const int bid = blockIdx.x;
    const long b = bid >> 7;                 // 128 tiles of 32 tokens per batch
    const int l0 = (bid & 127) * 32;
    const long base = b * LSEQ;

    // stage 34 rows (fp16 -> fp32)
    for (int idx = tid; idx < 34 * 128; idx += 256) {
        int r = idx >> 7, c = idx & 127;
        int lrow = (l0 + r - 1) & (LSEQ - 1);
        s_h[idx] = h2f(hin[(base + lrow) * 128 + c]);
    }
    __syncthreads();

    // GEMM1: u[m][n] = relu( sum_k cat[m][k] * W1[k][n] + b1[n] ),
    // cat[m][k] = s_h[(m + k/128)][k%128]  (prev,center,next row-shifted views)
    float acc[16];
    float b1n = b1[n];
#pragma unroll
    for (int j = 0; j < 16; j++) acc[j] = b1n;
    for (int k = 0; k < 384; k += 4) {
        float w0 = W1[(k + 0) * 128 + n];
        float w1 = W1[(k + 1) * 128 + n];
        float w2 = W1[(k + 2) * 128 + n];
        float w3 = W1[(k + 3) * 128 + n];
#pragma unroll
        for (int kk = 0; kk < 4; kk++) {
            int kg = k + kk;
            int blk = kg >> 7;
            int kcol = kg & 127;
            int bk = (tg + blk) * 128 + kcol;
            float w = (kk == 0) ? w0 : (kk == 1) ? w1 : (kk == 2) ? w2 : w3;
#pragma unroll
            for (int j = 0; j < 16; j++)
                acc[j] += s_h[bk + j * 256] * w;   // token m = 2j+tg -> row m+blk
        }
    }
#pragma unroll
    for (int j = 0; j < 16; j++) {
        int m = 2 * j + tg;
        s_u[m * 128 + n] = acc[j] > 0.f ? acc[j] : 0.f;
    }
    __syncthreads();

    // GEMM2: delta[m][n] = sum_k u[m][k] * W2[k][n] + b2[n]
    float acc2[16];
    float b2n = b2[n];
#pragma unroll
    for (int j = 0; j < 16; j++) acc2[j] = b2n;
    for (int k = 0; k < 128; k += 4) {
        float w0 = W2[(k + 0) * 128 + n];
        float w1 = W2[(k + 1) * 128 + n];
        float w2 = W2[(k + 2) * 128 + n];
        float w3 = W2[(k + 3) * 128 + n];
#pragma unroll
        for (int kk = 0; kk < 4; kk++) {
            float w = (kk == 0) ? w0 : (kk == 1) ? w1 : (kk == 2) ? w2 : w3;
            int bk = tg * 128 + k + kk;
#pragma unroll
            for (int j = 0; j < 16; j++)
                acc2[j] += s_u[bk + j * 256] * w;
        }
    }
    // x = h + delta  (must not overwrite s_u until all GEMM2 reads done)
    float xv[16];
#pragma unroll
    for (int j = 0; j < 16; j++) {
        int m = 2 * j + tg;
        xv[j] = acc2[j] + s_h[(m + 1) * 128 + n];   // center row residual
    }
    __syncthreads();
#pragma unroll
    for (int j = 0; j < 16; j++) {
        int m = 2 * j + tg;
        s_u[m * 128 + n] = xv[j];
    }
    __syncthreads();

    // LN stats per token (two-pass, serial by 32 threads)
    if (tid < 32) {
        int m = tid;
        float sum = 0.f;
        for (int c = 0; c < 128; c++) sum += s_u[m * 128 + c];
        float mu = sum * (1.f / 128.f);
        float ss = 0.f;
        for (int c = 0; c < 128; c++) {
            float d = s_u[m * 128 + c] - mu;
            ss += d * d;
        }
        s_mu[m] = mu;
        s_rs[m] = rsqrtf(ss * (1.f / 128.f) + EPS);
    }
    __syncthreads();

    float gn = gamma[n], bn = beta[n];
#pragma unroll
    for (int j = 0; j < 16; j++) {
        int m = 2 * j + tg;
        float y = (xv[j] - s_mu[m]) * s_rs[m] * gn + bn;
        hout[(base + l0 + m) * 128 + n] = f2h(y > 0.f ? y : 0.f);
    }
}

// ---- combine: hc[b][l] = 0.5*(hf[b][l] + hr[b][L-1-l]); write hc fp16 at hr's OWN
// (flipped) slot (race-free: each global row of hr read+written by exactly one wave);
// also raw scores[b][l].
__global__ void combine_kernel(const unsigned short* __restrict__ hf,
                               unsigned short* __restrict__ hr,
                               const float* __restrict__ Ws, const float* __restrict__ bs,
                               float* __restrict__ scores) {
    int tid = threadIdx.x;
    int wave = tid >> 6, lane = tid & 63;
    long wid = (long)blockIdx.x * 4 + wave;   // 8192 waves, 32 rows each
    float w0 = Ws[lane * 2], w1 = Ws[lane * 2 + 1];
    float bsv = bs[0];
    for (int r = 0; r < 32; r++) {
        long row = wid * 32 + r;
        long b = row >> 12;
        int l = (int)(row & (LSEQ - 1));
        long rowf = (b << 12) | (LSEQ - 1 - l);
        unsigned int f = *reinterpret_cast<const unsigned int*>(hf + row * 128 + lane * 2);
        unsigned int g = *reinterpret_cast<const unsigned int*>(hr + rowf * 128 + lane * 2);
        float h0v = 0.5f * (h2f(f & 0xffff) + h2f(g & 0xffff));
        float h1v = 0.5f * (h2f(f >> 16) + h2f(g >> 16));
        unsigned int packed = ((unsigned int)f2h(h1v) << 16) | (unsigned int)f2h(h0v);
        *reinterpret_cast<unsigned int*>(hr + rowf * 128 + lane * 2) = packed;  // hc, flipped
        float p = h0v * w0 + h1v * w1;
#pragma unroll
        for (int msk = 1; msk < 64; msk <<= 1) p += __shfl_xor(p, msk, 64);
        if (lane == 0) scores[row] = p + bsv;
    }
}

// ---------------- softmax over L per batch -------------------------------------------
__global__ void softmax_kernel(float* __restrict__ scores) {
    __shared__ float red[8];
    float* s = scores + (long)blockIdx.x * LSEQ;
    int tid = threadIdx.x;
    int wave = tid >> 6, lane = tid & 63;
    float v[16];
    float mx = -1e30f;
#pragma unroll
    for (int i = 0; i < 16; i++) { v[i] = s[i * 256 + tid]; mx = fmaxf(mx, v[i]); }
#pragma unroll
    for (int msk = 1; msk < 64; msk <<= 1) mx = fmaxf(mx, __shfl_xor(mx, msk, 64));
    if (lane == 0) red[wave] = mx;
    __syncthreads();
    mx = fmaxf(fmaxf(red[0], red[1]), fmaxf(red[2], red[3]));
    float sum = 0.f;
#pragma unroll
    for (int i = 0; i < 16; i++) { v[i] = __expf(v[i] - mx); sum += v[i]; }
#pragma unroll
    for (int msk = 1; msk < 64; msk <<= 1) sum += __shfl_xor(sum, msk, 64);
    if (lane == 0) red[4 + wave] = sum;
    __syncthreads();
    float inv = 1.f / (red[4] + red[5] + red[6] + red[7]);
#pragma unroll
    for (int i = 0; i < 16; i++) s[i * 256 + tid] = v[i] * inv;
}

// ---------------- expand: h_out[b][l] = fp32( hc_flipped[b][L-1-l] ) ------------------
__global__ void expand_kernel(const unsigned short* __restrict__ hcf,
                              float* __restrict__ h_out) {
    long pid = (long)blockIdx.x * 256 + threadIdx.x;   // 16,777,216 fp16-pairs
    long row = pid >> 6;
    int pr = (int)(pid & 63);
    long b = row >> 12;
    int l = (int)(row & (LSEQ - 1));
    long rowf = (b << 12) | (LSEQ - 1 - l);
    unsigned int u = reinterpret_cast<const unsigned int*>(hcf)[rowf * 64 + pr];
    float2 v;
    v.x = h2f(u & 0xffff);
    v.y = h2f(u >> 16);
    reinterpret_cast<float2*>(h_out)[row * 64 + pr] = v;
}

__global__ void zero_pooled(float* __restrict__ pooled) {
    int id = blockIdx.x * 256 + threadIdx.x;
    if (id < BATCH * HID) pooled[id] = 0.f;
}

// pooled[b][c] = sum_l w[b][l] h[b][l][c] = sum_j w[b][L-1-j] * hcf[b][j][c]
__global__ void pooled_kernel(const unsigned short* __restrict__ hcf,
                              const float* __restrict__ wts,
                              float* __restrict__ pooled) {
    int b = blockIdx.x >> 4, chunk = blockIdx.x & 15;   // 16 chunks of 256 rows
    int tid = threadIdx.x;
    int c = tid & 127, half = tid >> 7;
    float acc = 0.f;
    for (int i = 0; i < 128; i++) {
        int j = chunk * 256 + half + i * 2;
        acc += wts[(long)b * LSEQ + (LSEQ - 1 - j)] * h2f(hcf[((long)b * LSEQ + j) * 128 + c]);
    }
    atomicAdd(&pooled[b * 128 + c], acc);
}

// ---------------- launcher ------------------------------------------------------------
extern "C" void kernel_launch(void* const* d_in, const int* in_sizes, int n_in,
                              void* d_out, int out_size, void* d_ws, size_t ws_size,
                              hipStream_t stream) {
    const float* tokens = (const float*)d_in[0];
    const float* Wp     = (const float*)d_in[1];
    const float* bp     = (const float*)d_in[2];
    const float* W1     = (const float*)d_in[3];
    const float* b1     = (const float*)d_in[4];
    const float* W2     = (const float*)d_in[5];
    const float* b2     = (const float*)d_in[6];
    const float* gamma  = (const float*)d_in[7];
    const float* beta   = (const float*)d_in[8];
    const float* Ws     = (const float*)d_in[9];
    const float* bs     = (const float*)d_in[10];

    float* h_out  = (float*)d_out;                       // [B,L,128] fp32 (written at end)
    float* pooled = (float*)d_out + (long)BATCH * LSEQ * HID;

    const long NTOK = (long)BATCH * LSEQ * HID;          // 33,554,432 elements
    // ws: scores (1 MiB) + P (64 MiB)  -> 65 MiB total
    char* ws = (char*)d_ws;
    float* scores = (float*)ws;
    unsigned short* P = (unsigned short*)(ws + (long)BATCH * LSEQ * 4);

    // A, Bb ping-pong inside d_out's h region
    unsigned short* A  = (unsigned short*)d_out;
    unsigned short* Bb = A + NTOK;

    const int PGRID = (int)(NTOK / 256);
    const int NBLK = BATCH * (LSEQ / 32);   // 8192 blocks of 32 tokens

    // forward: proj -> P; P->A->Bb->A->Bb  (fwd final = Bb)
    proj_kernel<<<PGRID, 256, 0, stream>>>(tokens, Wp, bp, P, 0);
    {
        unsigned short* fin[4] = {P, A, Bb, A};
        unsigned short* fot[4] = {A, Bb, A, Bb};
        for (int i = 0; i < 4; i++)
            layer_simple<<<NBLK, 256, 0, stream>>>(fin[i], fot[i],
                W1 + (long)i * 384 * 128, W2 + (long)i * 128 * 128,
                b1 + i * 128, b2 + i * 128, gamma + i * 128, beta + i * 128);
    }
    // reverse (LITERAL): proj on flipped tokens -> P; same layers; final = P
    proj_kernel<<<PGRID, 256, 0, stream>>>(tokens, Wp, bp, P, 1);
    {
        unsigned short* rin[4] = {P, A, P, A};
        unsigned short* rot[4] = {A, P, A, P};
        for (int i = 0; i < 4; i++)
            layer_simple<<<NBLK, 256, 0, stream>>>(rin[i], rot[i],
                W1 + (long)i * 384 * 128, W2 + (long)i * 128 * 128,
                b1 + i * 128, b2 + i * 128, gamma + i * 128, beta + i * 128);
    }

    combine_kernel<<<2048, 256, 0, stream>>>(Bb, P, Ws, bs, scores);  // hc (flipped) -> P
    softmax_kernel<<<BATCH, 256, 0, stream>>>(scores);
    expand_kernel<<<65536, 256, 0, stream>>>(P, h_out);               // un-flip + fp32
    zero_pooled<<<32, 256, 0, stream>>>(pooled);
    pooled_kernel<<<BATCH * 16, 256, 0, stream>>>(P, scores, pooled);
}

// Round 5
// 1490.165 us; speedup vs baseline: 3.5285x; 3.5285x over previous
//
#include <hip/hip_runtime.h>
#include <hip/hip_fp16.h>

#define HID 128
#define LSEQ 4096
#define BATCH 64
#define EPS 1e-5f
#define LDH 136  // LDS leading dim in fp16 elems (128 + 8 pad, 16B aligned)

typedef __attribute__((ext_vector_type(8))) short short8;
typedef __attribute__((ext_vector_type(8))) _Float16 half8;
typedef __attribute__((ext_vector_type(4))) float floatx4;

__device__ inline unsigned short f2h(float f) {
    _Float16 h = (_Float16)f;
    return __builtin_bit_cast(unsigned short, h);
}
__device__ inline float h2f(unsigned short u) {
    return (float)__builtin_bit_cast(_Float16, u);
}

// ---------------- projection: out[b][l] = proj(tokens[b][ flip ? L-1-l : l ]) ---------
__global__ void proj_kernel(const float* __restrict__ tokens, const float* __restrict__ Wp,
                            const float* __restrict__ bp, unsigned short* __restrict__ out,
                            int flip) {
    long id = (long)blockIdx.x * 256 + threadIdx.x;    // B*L*128
    int c = (int)(id & 127);
    long row = id >> 7;
    int l = (int)(row & (LSEQ - 1));
    long b = row >> 12;
    int ls = flip ? (LSEQ - 1 - l) : l;
    const float* t = tokens + (b * LSEQ + ls) * 8;
    float acc = bp[c];
#pragma unroll
    for (int j = 0; j < 8; j++) acc += t[j] * Wp[j * 128 + c];
    out[id] = f2h(acc);
}

// ---- fused layer (MFMA): GEMM1(K=384) -> relu -> GEMM2(K=128) -> +res -> LN -> relu --
// 128-token tiles, 4 waves. Weights read DIRECTLY from fp32 [k][n] arrays (no prep).
__launch_bounds__(256, 2)
__global__ void layer_mfma(const unsigned short* __restrict__ hin,
                           unsigned short* __restrict__ hout,
                           const float* __restrict__ W1,   // [384][128] fp32, this layer
                           const float* __restrict__ W2,   // [128][128] fp32, this layer
                           const float* __restrict__ b1, const float* __restrict__ b2,
                           const float* __restrict__ gamma, const float* __restrict__ beta) {
    __shared__ unsigned short s_hin[130 * LDH];
    __shared__ unsigned short s_u[128 * LDH];

    const int tid = threadIdx.x;
    const int wave = tid >> 6;
    const int lane = tid & 63;
    const int quad = lane >> 4;
    const int l16 = lane & 15;

    const int bid = blockIdx.x;
    const long b = bid >> 5;          // 32 tiles of 128 tokens per batch
    const int l0 = (bid & 31) * 128;
    const long base = b * LSEQ;

    // stage rows l0-1 .. l0+128 (circular in L) -> LDS, 16B chunks
    for (int c = tid; c < 130 * 16; c += 256) {
        int r = c >> 4;
        int cc = (c & 15) * 8;
        int lrow = (l0 + r - 1) & (LSEQ - 1);
        short8 v = *reinterpret_cast<const short8*>(hin + (base + lrow) * 128 + cc);
        *reinterpret_cast<short8*>(&s_hin[r * LDH + cc]) = v;
    }

    // preload GEMM1 B-fragments straight from fp32 W1 [k][n] (n-split: wave's cols)
    half8 bfrag1[2][12];
    float b1v[2];
#pragma unroll
    for (int nt = 0; nt < 2; nt++) {
        int n = wave * 32 + nt * 16 + l16;
        b1v[nt] = b1[n];
#pragma unroll
        for (int ks = 0; ks < 12; ks++) {
            half8 v;
#pragma unroll
            for (int j = 0; j < 8; j++) {
                int k = ks * 32 + quad * 8 + j;          // global cat-k 0..383
                v[j] = (_Float16)W1[(long)k * 128 + n];
            }
            bfrag1[nt][ks] = v;
        }
    }

    __syncthreads();

    // GEMM1: u' = cat @ W1   (A k-blocks = row-shifted views of s_hin)
    floatx4 acc1[8][2];
#pragma unroll
    for (int mt = 0; mt < 8; mt++)
#pragma unroll
        for (int nt = 0; nt < 2; nt++) acc1[mt][nt] = (floatx4){0.f, 0.f, 0.f, 0.f};

#pragma unroll
    for (int ks = 0; ks < 12; ks++) {
        const int j = ks >> 2;                // shift block: 0=prev,1=center,2=next
        const int koff = ks * 32 - j * 128;   // col within block
#pragma unroll
        for (int mt = 0; mt < 8; mt++) {
            int m = mt * 16 + l16;
            half8 a = *reinterpret_cast<const half8*>(&s_hin[(m + j) * LDH + koff + quad * 8]);
            acc1[mt][0] = __builtin_amdgcn_mfma_f32_16x16x32_f16(a, bfrag1[0][ks], acc1[mt][0], 0, 0, 0);
            acc1[mt][1] = __builtin_amdgcn_mfma_f32_16x16x32_f16(a, bfrag1[1][ks], acc1[mt][1], 0, 0, 0);
        }
    }

    // epilogue1: u = relu(acc1 + b1) -> LDS [m][n] fp16   (C/D: row=quad*4+reg, col=l16)
#pragma unroll
    for (int mt = 0; mt < 8; mt++)
#pragma unroll
        for (int nt = 0; nt < 2; nt++) {
            int colb = wave * 32 + nt * 16 + l16;
#pragma unroll
            for (int reg = 0; reg < 4; reg++) {
                int row = mt * 16 + quad * 4 + reg;
                float v = acc1[mt][nt][reg] + b1v[nt];
                s_u[row * LDH + colb] = f2h(v > 0.f ? v : 0.f);
            }
        }
    __syncthreads();

    // preload GEMM2 B-fragments from fp32 W2 [k][n] + per-col params (m-split for LN)
    half8 bfrag2[8][4];
    float b2v[8], gamv[8], betv[8];
#pragma unroll
    for (int nt = 0; nt < 8; nt++) {
        int n = nt * 16 + l16;
        b2v[nt] = b2[n]; gamv[nt] = gamma[n]; betv[nt] = beta[n];
#pragma unroll
        for (int ks = 0; ks < 4; ks++) {
            half8 v;
#pragma unroll
            for (int j = 0; j < 8; j++) {
                int k = ks * 32 + quad * 8 + j;
                v[j] = (_Float16)W2[(long)k * 128 + n];
            }
            bfrag2[nt][ks] = v;
        }
    }

    floatx4 acc2[2][8];
#pragma unroll
    for (int mt2 = 0; mt2 < 2; mt2++)
#pragma unroll
        for (int nt = 0; nt < 8; nt++) acc2[mt2][nt] = (floatx4){0.f, 0.f, 0.f, 0.f};

#pragma unroll
    for (int ks = 0; ks < 4; ks++)
#pragma unroll
        for (int mt2 = 0; mt2 < 2; mt2++) {
            int m = (wave * 2 + mt2) * 16 + l16;
            half8 a = *reinterpret_cast<const half8*>(&s_u[m * LDH + ks * 32 + quad * 8]);
#pragma unroll
            for (int nt = 0; nt < 8; nt++)
                acc2[mt2][nt] = __builtin_amdgcn_mfma_f32_16x16x32_f16(a, bfrag2[nt][ks], acc2[mt2][nt], 0, 0, 0);
        }

    // epilogue2: x = res + delta; LN over 128 (l16 butterfly); relu; fp16 store
#pragma unroll
    for (int mt2 = 0; mt2 < 2; mt2++) {
        float x[8][4];
        float sum[4] = {0.f, 0.f, 0.f, 0.f}, ssq[4] = {0.f, 0.f, 0.f, 0.f};
#pragma unroll
        for (int nt = 0; nt < 8; nt++) {
            int col = nt * 16 + l16;
#pragma unroll
            for (int reg = 0; reg < 4; reg++) {
                int row = (wave * 2 + mt2) * 16 + quad * 4 + reg;
                float hv = h2f(s_hin[(row + 1) * LDH + col]);  // center row residual
                float v = acc2[mt2][nt][reg] + b2v[nt] + hv;
                x[nt][reg] = v;
                sum[reg] += v;
                ssq[reg] += v * v;
            }
        }
#pragma unroll
        for (int msk = 1; msk < 16; msk <<= 1)
#pragma unroll
            for (int reg = 0; reg < 4; reg++) {
                sum[reg] += __shfl_xor(sum[reg], msk, 64);
                ssq[reg] += __shfl_xor(ssq[reg], msk, 64);
            }
#pragma unroll
        for (int reg = 0; reg < 4; reg++) {
            float mu = sum[reg] * (1.f / 128.f);
            float var = ssq[reg] * (1.f / 128.f) - mu * mu;
            float rstd = rsqrtf(var + EPS);
            int row = (wave * 2 + mt2) * 16 + quad * 4 + reg;
            long gb = (base + l0 + row) * 128;
#pragma unroll
            for (int nt = 0; nt < 8; nt++) {
                float y = (x[nt][reg] - mu) * rstd * gamv[nt] + betv[nt];
                hout[gb + nt * 16 + l16] = f2h(y > 0.f ? y : 0.f);
            }
        }
    }
}

// ---- combine: hc[b][l] = 0.5*(hf[b][l] + hr[b][L-1-l]); write hc fp16 at hr's OWN
// (flipped) slot (race-free); also raw scores[b][l].
__global__ void combine_kernel(const unsigned short* __restrict__ hf,
                               unsigned short* __restrict__ hr,
                               const float* __restrict__ Ws, const float* __restrict__ bs,
                               float* __restrict__ scores) {
    int tid = threadIdx.x;
    int wave = tid >> 6, lane = tid & 63;
    long wid = (long)blockIdx.x * 4 + wave;   // 8192 waves, 32 rows each
    float w0 = Ws[lane * 2], w1 = Ws[lane * 2 + 1];
    float bsv = bs[0];
    for (int r = 0; r < 32; r++) {
        long row = wid * 32 + r;
        long b = row >> 12;
        int l = (int)(row & (LSEQ - 1));
        long rowf = (b << 12) | (LSEQ - 1 - l);
        unsigned int f = *reinterpret_cast<const unsigned int*>(hf + row * 128 + lane * 2);
        unsigned int g = *reinterpret_cast<const unsigned int*>(hr + rowf * 128 + lane * 2);
        float h0v = 0.5f * (h2f(f & 0xffff) + h2f(g & 0xffff));
        float h1v = 0.5f * (h2f(f >> 16) + h2f(g >> 16));
        unsigned int packed = ((unsigned int)f2h(h1v) << 16) | (unsigned int)f2h(h0v);
        *reinterpret_cast<unsigned int*>(hr + rowf * 128 + lane * 2) = packed;  // hc, flipped
        float p = h0v * w0 + h1v * w1;
#pragma unroll
        for (int msk = 1; msk < 64; msk <<= 1) p += __shfl_xor(p, msk, 64);
        if (lane == 0) scores[row] = p + bsv;
    }
}

// ---------------- softmax over L per batch -------------------------------------------
__global__ void softmax_kernel(float* __restrict__ scores) {
    __shared__ float red[8];
    float* s = scores + (long)blockIdx.x * LSEQ;
    int tid = threadIdx.x;
    int wave = tid >> 6, lane = tid & 63;
    float v[16];
    float mx = -1e30f;
#pragma unroll
    for (int i = 0; i < 16; i++) { v[i] = s[i * 256 + tid]; mx = fmaxf(mx, v[i]); }
#pragma unroll
    for (int msk = 1; msk < 64; msk <<= 1) mx = fmaxf(mx, __shfl_xor(mx, msk, 64));
    if (lane == 0) red[wave] = mx;
    __syncthreads();
    mx = fmaxf(fmaxf(red[0], red[1]), fmaxf(red[2], red[3]));
    float sum = 0.f;
#pragma unroll
    for (int i = 0; i < 16; i++) { v[i] = __expf(v[i] - mx); sum += v[i]; }
#pragma unroll
    for (int msk = 1; msk < 64; msk <<= 1) sum += __shfl_xor(sum, msk, 64);
    if (lane == 0) red[4 + wave] = sum;
    __syncthreads();
    float inv = 1.f / (red[4] + red[5] + red[6] + red[7]);
#pragma unroll
    for (int i = 0; i < 16; i++) s[i * 256 + tid] = v[i] * inv;
}

// ---------------- expand: h_out[b][l] = fp32( hc_flipped[b][L-1-l] ) ------------------
__global__ void expand_kernel(const unsigned short* __restrict__ hcf,
                              float* __restrict__ h_out) {
    long pid = (long)blockIdx.x * 256 + threadIdx.x;   // 16,777,216 fp16-pairs
    long row = pid >> 6;
    int pr = (int)(pid & 63);
    long b = row >> 12;
    int l = (int)(row & (LSEQ - 1));
    long rowf = (b << 12) | (LSEQ - 1 - l);
    unsigned int u = reinterpret_cast<const unsigned int*>(hcf)[rowf * 64 + pr];
    float2 v;
    v.x = h2f(u & 0xffff);
    v.y = h2f(u >> 16);
    reinterpret_cast<float2*>(h_out)[row * 64 + pr] = v;
}

__global__ void zero_pooled(float* __restrict__ pooled) {
    int id = blockIdx.x * 256 + threadIdx.x;
    if (id < BATCH * HID) pooled[id] = 0.f;
}

// pooled[b][c] = sum_j w[b][L-1-j] * hcf[b][j][c]
__global__ void pooled_kernel(const unsigned short* __restrict__ hcf,
                              const float* __restrict__ wts,
                              float* __restrict__ pooled) {
    int b = blockIdx.x >> 4, chunk = blockIdx.x & 15;   // 16 chunks of 256 rows
    int tid = threadIdx.x;
    int c = tid & 127, half = tid >> 7;
    float acc = 0.f;
    for (int i = 0; i < 128; i++) {
        int j = chunk * 256 + half + i * 2;
        acc += wts[(long)b * LSEQ + (LSEQ - 1 - j)] * h2f(hcf[((long)b * LSEQ + j) * 128 + c]);
    }
    atomicAdd(&pooled[b * 128 + c], acc);
}

// ---------------- launcher ------------------------------------------------------------
extern "C" void kernel_launch(void* const* d_in, const int* in_sizes, int n_in,
                              void* d_out, int out_size, void* d_ws, size_t ws_size,
                              hipStream_t stream) {
    const float* tokens = (const float*)d_in[0];
    const float* Wp     = (const float*)d_in[1];
    const float* bp     = (const float*)d_in[2];
    const float* W1     = (const float*)d_in[3];
    const float* b1     = (const float*)d_in[4];
    const float* W2     = (const float*)d_in[5];
    const float* b2     = (const float*)d_in[6];
    const float* gamma  = (const float*)d_in[7];
    const float* beta   = (const float*)d_in[8];
    const float* Ws     = (const float*)d_in[9];
    const float* bs     = (const float*)d_in[10];

    float* h_out  = (float*)d_out;                       // [B,L,128] fp32 (written at end)
    float* pooled = (float*)d_out + (long)BATCH * LSEQ * HID;

    const long NTOK = (long)BATCH * LSEQ * HID;          // 33,554,432 elements
    // ws: scores (1 MiB) + P (64 MiB)  -> 65 MiB total (R4-proven)
    char* ws = (char*)d_ws;
    float* scores = (float*)ws;
    unsigned short* P = (unsigned short*)(ws + (long)BATCH * LSEQ * 4);

    // A, Bb ping-pong inside d_out's h region
    unsigned short* A  = (unsigned short*)d_out;
    unsigned short* Bb = A + NTOK;

    const int PGRID = (int)(NTOK / 256);
    const int NBLK = BATCH * (LSEQ / 128);   // 2048 blocks of 128 tokens

    // forward: proj -> P; P->A->Bb->A->Bb  (fwd final = Bb)
    proj_kernel<<<PGRID, 256, 0, stream>>>(tokens, Wp, bp, P, 0);
    {
        unsigned short* fin[4] = {P, A, Bb, A};
        unsigned short* fot[4] = {A, Bb, A, Bb};
        for (int i = 0; i < 4; i++)
            layer_mfma<<<NBLK, 256, 0, stream>>>(fin[i], fot[i],
                W1 + (long)i * 384 * 128, W2 + (long)i * 128 * 128,
                b1 + i * 128, b2 + i * 128, gamma + i * 128, beta + i * 128);
    }
    // reverse (LITERAL): proj on flipped tokens -> P; same layers; final = P
    proj_kernel<<<PGRID, 256, 0, stream>>>(tokens, Wp, bp, P, 1);
    {
        unsigned short* rin[4] = {P, A, P, A};
        unsigned short* rot[4] = {A, P, A, P};
        for (int i = 0; i < 4; i++)
            layer_mfma<<<NBLK, 256, 0, stream>>>(rin[i], rot[i],
                W1 + (long)i * 384 * 128, W2 + (long)i * 128 * 128,
                b1 + i * 128, b2 + i * 128, gamma + i * 128, beta + i * 128);
    }

    combine_kernel<<<2048, 256, 0, stream>>>(Bb, P, Ws, bs, scores);  // hc (flipped) -> P
    softmax_kernel<<<BATCH, 256, 0, stream>>>(scores);
    expand_kernel<<<65536, 256, 0, stream>>>(P, h_out);               // un-flip + fp32
    zero_pooled<<<32, 256, 0, stream>>>(pooled);
    pooled_kernel<<<BATCH * 16, 256, 0, stream>>>(P, scores, pooled);
}